// Round 4
// baseline (177.177 us; speedup 1.0000x reference)
//
#include <hip/hip_runtime.h>
#include <hip/hip_bf16.h>
#include <math.h>

#define N_ROWS 8192
#define DIM 256
#define NCLS 128
// scale folded into normalized rows: sqrt((1/0.07) * log2(e))
#define ROW_SCALE 4.539816f
#define CLAMP_Y 14.426950408889634f   // 10 * log2(e)
#define LN2F 0.6931471805599453f
#define NBLK 544                      // 32 pairs x 17 chunks

typedef short bf16x8 __attribute__((ext_vector_type(8)));
typedef float f32x4 __attribute__((ext_vector_type(4)));

#define AS1 __attribute__((address_space(1)))
#define AS3 __attribute__((address_space(3)))

__device__ __forceinline__ void load16_to_lds(const void* g, void* lds) {
  // LDS dest = wave-uniform base + lane*16 (HW rule); gptr is per-lane
  __builtin_amdgcn_global_load_lds((const AS1 void*)g, (AS3 void*)lds, 16, 0, 0);
}

__device__ __forceinline__ unsigned short f2bf(float x) {
  union { __hip_bfloat16 b; unsigned short u; } cv;
  cv.b = __float2bfloat16(x);
  return cv.u;
}

__device__ __forceinline__ float fast_exp2(float x) {
#if __has_builtin(__builtin_amdgcn_exp2f)
  return __builtin_amdgcn_exp2f(x);
#else
  return exp2f(x);
#endif
}

// ---------------- row-normalize*ROW_SCALE -> bf16, zero S/P/done ------------
__global__ __launch_bounds__(256) void normalize_kernel(const float* __restrict__ f,
                                                        unsigned short* __restrict__ fnb,
                                                        float* __restrict__ S,
                                                        float* __restrict__ P,
                                                        unsigned int* __restrict__ done) {
  const int row = blockIdx.x * 4 + (threadIdx.x >> 6);
  const int l = threadIdx.x & 63;
  const float4 v = ((const float4*)(f + (size_t)row * DIM))[l];
  float ss = v.x * v.x + v.y * v.y + v.z * v.z + v.w * v.w;
#pragma unroll
  for (int m = 32; m >= 1; m >>= 1) ss += __shfl_xor(ss, m, 64);
  const float inv = ROW_SCALE / fmaxf(sqrtf(ss), 1e-6f);
  ushort4 o;
  o.x = f2bf(v.x * inv);
  o.y = f2bf(v.y * inv);
  o.z = f2bf(v.z * inv);
  o.w = f2bf(v.w * inv);
  ((ushort4*)(fnb + (size_t)row * DIM))[l] = o;
  if (l == 0) { S[row] = 0.f; P[row] = 0.f; }
  if (blockIdx.x == 0 && threadIdx.x == 0) *done = 0u;
}

// ---------------- barrier-free triangular GEMM + fused finalize -------------
// 544 blocks; block = (pair, chunk): pair p owns rows {p, 63-p} of the 64x64
// tile-triangle (exactly 65 tiles), chunk = 4 consecutive tiles of that list.
// A(bi) resident in LDS (64 KB, one barrier per stage; ~32 boundary blocks
// restage once). B-fragments load DIRECTLY global->VGPR from L2 (fnb = 4 MB,
// L2-resident) with 1-deep kt prefetch -> ZERO barriers in the K/j loops.
// Row sums persist in registers per wave across each bi-run; col sums via
// symmetry with direct per-quad atomics. Diagonal contributes exactly e=1 /
// y=CLAMP_Y (self-sim >> clamp), corrected in the fused finalize, which runs
// in the last-done block (device-scope counter).
__global__ __launch_bounds__(256) void simloss_tri(
    const unsigned short* __restrict__ fnb, const int* __restrict__ labels,
    float* __restrict__ S, float* __restrict__ P,
    unsigned int* __restrict__ done, float* __restrict__ out) {
  __shared__ __align__(16) unsigned short Atile[128 * 256];  // 64 KB
  __shared__ unsigned int lastflag;

  const int tid = threadIdx.x;
  const int w = tid >> 6, l = tid & 63;
  const int wr = w >> 1, wc = w & 1;
  const int ln15 = l & 15, q = l >> 4;

  // balanced schedule: pair p = rows {p, 63-p}, 65 tiles; chunk of <=4
  const int pair = blockIdx.x / 17;
  const int chunk = blockIdx.x % 17;
  const int rowA = pair, rowB = 63 - pair;
  const int nA = 64 - rowA;            // tiles in first row
  const int g0 = chunk * 4;
  const int g1 = (g0 + 4 < 65) ? g0 + 4 : 65;

  int cur_bi = -1;
  float rs[16], rp[16];
  int rowlab[16];

  auto flush_rows = [&]() {
#pragma unroll
    for (int m = 1; m <= 8; m <<= 1)
#pragma unroll
      for (int t = 0; t < 16; ++t) {
        rs[t] += __shfl_xor(rs[t], m, 64);
        rp[t] += __shfl_xor(rp[t], m, 64);
      }
    if (ln15 == 0) {
#pragma unroll
      for (int t = 0; t < 16; ++t) {
        const int rl = cur_bi * 128 + wr * 64 + (t >> 2) * 16 + q * 4 + (t & 3);
        atomicAdd(&S[rl], rs[t]);
        atomicAdd(&P[rl], rp[t]);
      }
    }
  };

  for (int g = g0; g < g1; ++g) {
    int bi, bj;
    if (g < nA) { bi = rowA; bj = rowA + g; }
    else        { bi = rowB; bj = rowB + (g - nA); }

    if (bi != cur_bi) {
      if (cur_bi >= 0) {
        flush_rows();
        __syncthreads();  // all waves done reading old Atile
      }
      cur_bi = bi;
      const int ibase = bi * 128;
      // stage A [128][256]; 16B chunk c of row r stored at c^(r&7)
#pragma unroll
      for (int r = 0; r < 16; ++r) {
        const int off = r * 4096 + w * 1024 + l * 16;
        const int row = off >> 9;                    // 512 B per row
        const int c = ((off >> 4) & 31) ^ (row & 7);
        load16_to_lds((const char*)fnb + (size_t)(ibase + row) * 512 + c * 16,
                      (char*)Atile + r * 4096 + w * 1024);
      }
      __syncthreads();  // staging complete (vmcnt drained by compiler)
#pragma unroll
      for (int mi = 0; mi < 4; ++mi)
#pragma unroll
        for (int rg = 0; rg < 4; ++rg)
          rowlab[mi * 4 + rg] = labels[ibase + wr * 64 + mi * 16 + q * 4 + rg];
#pragma unroll
      for (int t = 0; t < 16; ++t) { rs[t] = 0.f; rp[t] = 0.f; }
    }

    const int jbase = bj * 128;
    int labJ[4];
#pragma unroll
    for (int ni = 0; ni < 4; ++ni)
      labJ[ni] = labels[jbase + wc * 64 + ni * 16 + ln15];

    f32x4 acc[4][4];
#pragma unroll
    for (int mi = 0; mi < 4; ++mi)
#pragma unroll
      for (int ni = 0; ni < 4; ++ni) acc[mi][ni] = (f32x4)0.0f;

    // B fragments straight from global (L2-resident): row n, 16B chunk (kt*4+q)
    const char* bbase = (const char*)fnb +
        ((size_t)jbase + (size_t)wc * 64) * 512 + (size_t)q * 16;

    bf16x8 bcur[4], bnxt[4];
#pragma unroll
    for (int ni = 0; ni < 4; ++ni)
      bcur[ni] = *(const bf16x8*)(bbase + (ni * 16 + ln15) * 512);

#pragma unroll
    for (int kt = 0; kt < 8; ++kt) {
      if (kt < 7) {
#pragma unroll
        for (int ni = 0; ni < 4; ++ni)
          bnxt[ni] = *(const bf16x8*)(bbase + (ni * 16 + ln15) * 512 + (kt + 1) * 64);
      }
      bf16x8 af[4];
#pragma unroll
      for (int mi = 0; mi < 4; ++mi) {
        const int row = wr * 64 + mi * 16 + ln15;
        const int c = (kt * 4 + q) ^ (row & 7);
        af[mi] = *(const bf16x8*)((const char*)Atile + row * 512 + c * 16);
      }
#pragma unroll
      for (int mi = 0; mi < 4; ++mi)
#pragma unroll
        for (int ni = 0; ni < 4; ++ni)
          acc[mi][ni] = __builtin_amdgcn_mfma_f32_16x16x32_bf16(af[mi], bcur[ni],
                                                                acc[mi][ni], 0, 0, 0);
      if (kt < 7) {
#pragma unroll
        for (int ni = 0; ni < 4; ++ni) bcur[ni] = bnxt[ni];
      }
    }

    // epilogue: exp-sum + positive-sim accumulate (rows persist; cols direct)
    float cs[4], cp[4];
#pragma unroll
    for (int t = 0; t < 4; ++t) { cs[t] = 0.f; cp[t] = 0.f; }
#pragma unroll
    for (int mi = 0; mi < 4; ++mi)
#pragma unroll
      for (int ni = 0; ni < 4; ++ni)
#pragma unroll
        for (int rg = 0; rg < 4; ++rg) {
          const float y = acc[mi][ni][rg];
          const float yc = fminf(CLAMP_Y, fmaxf(-CLAMP_Y, y));  // v_med3
          const float e = fast_exp2(yc - CLAMP_Y);
          const float pv = (labJ[ni] == rowlab[mi * 4 + rg]) ? yc : 0.0f;
          rs[mi * 4 + rg] += e;
          rp[mi * 4 + rg] += pv;
          cs[ni] += e;
          cp[ni] += pv;
        }

    if (bj != bi) {  // col sums -> rows of bj via symmetry
#pragma unroll
      for (int m = 16; m <= 32; m <<= 1)
#pragma unroll
        for (int t = 0; t < 4; ++t) {
          cs[t] += __shfl_xor(cs[t], m, 64);
          cp[t] += __shfl_xor(cp[t], m, 64);
        }
      if (q == 0) {
#pragma unroll
        for (int ni = 0; ni < 4; ++ni) {
          const int col = jbase + wc * 64 + ni * 16 + ln15;
          atomicAdd(&S[col], cs[ni]);
          atomicAdd(&P[col], cp[ni]);
        }
      }
    }
  }
  flush_rows();

  // ---- completion: last block performs the finalize ----
  __threadfence();   // release this thread's S/P atomics (device scope)
  __syncthreads();   // all threads' fences done before tid0 signals
  if (tid == 0) {
    const unsigned int old = __hip_atomic_fetch_add(done, 1u, __ATOMIC_ACQ_REL,
                                                    __HIP_MEMORY_SCOPE_AGENT);
    lastflag = (old == NBLK - 1) ? 1u : 0u;
  }
  __syncthreads();
  if (lastflag) {
    int* h = (int*)Atile;  // reuse LDS as label histogram
    if (tid < NCLS) h[tid] = 0;
    __syncthreads();
    for (int i = tid; i < N_ROWS; i += 256) atomicAdd(&h[labels[i]], 1);
    __syncthreads();
    float lsum = 0.f, vsum = 0.f;
    for (int i = tid; i < N_ROWS; i += 256) {
      const int cnt = h[labels[i]] - 1;  // positives excluding self
      if (cnt > 0) {
        const float s = __hip_atomic_load(&S[i], __ATOMIC_RELAXED,
                                          __HIP_MEMORY_SCOPE_AGENT);
        const float p = __hip_atomic_load(&P[i], __ATOMIC_RELAXED,
                                          __HIP_MEMORY_SCOPE_AGENT);
        const float lse = 10.0f + logf(s - 1.0f);   // remove diag e=1
        const float psum = p * LN2F - 10.0f;        // de-scale, remove diag
        lsum += lse - psum / (float)cnt;            // -mean_log_prob_pos
        vsum += 1.0f;
      }
    }
#pragma unroll
    for (int m = 32; m >= 1; m >>= 1) {
      lsum += __shfl_xor(lsum, m, 64);
      vsum += __shfl_xor(vsum, m, 64);
    }
    __shared__ float ls[4], vs[4];
    if (l == 0) { ls[w] = lsum; vs[w] = vsum; }
    __syncthreads();
    if (tid == 0) {
      float L = 0.f, V = 0.f;
      for (int k = 0; k < 4; ++k) { L += ls[k]; V += vs[k]; }
      out[0] = (V > 0.f) ? (L / fmaxf(V, 1.0f)) : 0.f;
    }
  }
}

extern "C" void kernel_launch(void* const* d_in, const int* in_sizes, int n_in,
                              void* d_out, int out_size, void* d_ws, size_t ws_size,
                              hipStream_t stream) {
  const float* feat = (const float*)d_in[0];
  const int* labels = (const int*)d_in[1];
  float* out = (float*)d_out;

  char* ws = (char*)d_ws;
  unsigned short* fnb = (unsigned short*)ws;            // bf16 [8192][256], 4 MB
  float* S = (float*)(ws + (size_t)N_ROWS * DIM * 2);   // [8192]
  float* P = S + N_ROWS;                                // [8192]
  unsigned int* done = (unsigned int*)(P + N_ROWS);     // [1]

  normalize_kernel<<<N_ROWS / 4, 256, 0, stream>>>(feat, fnb, S, P, done);
  simloss_tri<<<NBLK, 256, 0, stream>>>(fnb, labels, S, P, done, out);
}

// Round 5
// 138.024 us; speedup vs baseline: 1.2837x; 1.2837x over previous
//
#include <hip/hip_runtime.h>
#include <hip/hip_bf16.h>
#include <math.h>

#define N_ROWS 8192
#define DIM 256
#define NCLS 128
// scale folded into normalized rows: sqrt((1/0.07) * log2(e))
#define ROW_SCALE 4.539816f
#define CLAMP_Y 14.426950408889634f   // 10 * log2(e)
#define LN2F 0.6931471805599453f
#define NBLK 256                      // 32 pairs x 8 chunks, 1 block/CU

typedef short bf16x8 __attribute__((ext_vector_type(8)));
typedef float f32x4 __attribute__((ext_vector_type(4)));

#define AS1 __attribute__((address_space(1)))
#define AS3 __attribute__((address_space(3)))

__device__ __forceinline__ void load16_to_lds(const void* g, void* lds) {
  // LDS dest = wave-uniform base + lane*16 (HW rule); gptr is per-lane
  __builtin_amdgcn_global_load_lds((const AS1 void*)g, (AS3 void*)lds, 16, 0, 0);
}

__device__ __forceinline__ unsigned short f2bf(float x) {
  union { __hip_bfloat16 b; unsigned short u; } cv;
  cv.b = __float2bfloat16(x);
  return cv.u;
}

__device__ __forceinline__ float fast_exp2(float x) {
#if __has_builtin(__builtin_amdgcn_exp2f)
  return __builtin_amdgcn_exp2f(x);
#else
  return exp2f(x);
#endif
}

// ---------------- row-normalize*ROW_SCALE -> bf16, zero S/P/done ------------
__global__ __launch_bounds__(256) void normalize_kernel(const float* __restrict__ f,
                                                        unsigned short* __restrict__ fnb,
                                                        float* __restrict__ S,
                                                        float* __restrict__ P,
                                                        unsigned int* __restrict__ done) {
  const int row = blockIdx.x * 4 + (threadIdx.x >> 6);
  const int l = threadIdx.x & 63;
  const float4 v = ((const float4*)(f + (size_t)row * DIM))[l];
  float ss = v.x * v.x + v.y * v.y + v.z * v.z + v.w * v.w;
#pragma unroll
  for (int m = 32; m >= 1; m >>= 1) ss += __shfl_xor(ss, m, 64);
  const float inv = ROW_SCALE / fmaxf(sqrtf(ss), 1e-6f);
  ushort4 o;
  o.x = f2bf(v.x * inv);
  o.y = f2bf(v.y * inv);
  o.z = f2bf(v.z * inv);
  o.w = f2bf(v.w * inv);
  ((ushort4*)(fnb + (size_t)row * DIM))[l] = o;
  if (l == 0) { S[row] = 0.f; P[row] = 0.f; }
  if (blockIdx.x == 0 && threadIdx.x == 0) *done = 0u;
}

// ---------------- pipelined triangular GEMM + fused finalize ----------------
// 256 blocks (1/CU): block = (pair, chunk); pair p owns rows {p, 63-p} of the
// 64x64 tile-triangle (65 tiles), chunk = ~8 consecutive tiles. A-fragments
// live in REGISTERS (af[4][8], loaded once per bi via coalesced LDS staging).
// B is staged in half-K granules (32 KB) double-buffered: barrier -> issue
// next-half global_load_lds -> compute 4 kt -> barrier (drains a load issued
// a full compute phase earlier => latency hidden, 2 barriers/tile).
// ALL global traffic is contiguous 1KB/instr (R4 lesson: 16-segment strided
// loads choke the memory pipe). Row sums persist in regs per bi-run; col sums
// via symmetry with per-wave atomics. Diagonal contributes exactly e=1 /
// y=CLAMP_Y, corrected in the fused finalize (last-done block).
__global__ __launch_bounds__(256, 1) void simloss_tri(
    const unsigned short* __restrict__ fnb, const int* __restrict__ labels,
    float* __restrict__ S, float* __restrict__ P,
    unsigned int* __restrict__ done, float* __restrict__ out) {
  __shared__ __align__(16) unsigned short Abuf[2][128 * 128];  // 64 KB (2 K-halves)
  __shared__ __align__(16) unsigned short Bbuf[2][128 * 128];  // 64 KB (dbuf halves)
  __shared__ unsigned int lastflag;

  const int tid = threadIdx.x;
  const int w = tid >> 6, l = tid & 63;
  const int wr = w >> 1, wc = w & 1;
  const int ln15 = l & 15, q = l >> 4;

  const int pair = blockIdx.x >> 3;     // 0..31
  const int chunk = blockIdx.x & 7;     // 0..7
  const int rowA = pair, rowB = 63 - pair;
  const int nA = 64 - rowA;             // tiles in first row
  const int g0 = (65 * chunk) >> 3;
  const int g1 = (65 * (chunk + 1)) >> 3;

  // stage one 128x128-element K-half (32 KB) of rows [rowbase,rowbase+128).
  // dst rows are 256 B; 16B chunk c of row r stored at c^(r&7) (2-way free).
  // Source addresses per instr: contiguous 1 KB (coalesced).
  auto stage_half = [&](unsigned short* dst, int rowbase, int h) {
#pragma unroll
    for (int i = 0; i < 8; ++i) {
      const int off = i * 4096 + w * 1024 + l * 16;
      const int row = off >> 8;
      const int c = ((off >> 4) & 15) ^ (row & 7);
      load16_to_lds((const char*)fnb + (size_t)(rowbase + row) * 512 + h * 256 + c * 16,
                    (char*)dst + i * 4096 + w * 1024);
    }
  };

  bf16x8 af[4][8];      // A fragments, full K, in registers (128 VGPR)
  float rs[16], rp[16];
  int rowlab[16];
  int cur_bi = -1;

  auto flush_rows = [&]() {
#pragma unroll
    for (int m = 1; m <= 8; m <<= 1)
#pragma unroll
      for (int t = 0; t < 16; ++t) {
        rs[t] += __shfl_xor(rs[t], m, 64);
        rp[t] += __shfl_xor(rp[t], m, 64);
      }
    if (ln15 == 0) {
#pragma unroll
      for (int t = 0; t < 16; ++t) {
        const int rl = cur_bi * 128 + wr * 64 + (t >> 2) * 16 + q * 4 + (t & 3);
        atomicAdd(&S[rl], rs[t]);
        atomicAdd(&P[rl], rp[t]);
      }
    }
  };

  int bi0, bj0;
  if (g0 < nA) { bi0 = rowA; bj0 = rowA + g0; }
  else         { bi0 = rowB; bj0 = rowB + (g0 - nA); }
  stage_half(&Bbuf[0][0], bj0 * 128, 0);
  int pb = 0;

  for (int g = g0; g < g1; ++g) {
    int bi, bj;
    if (g < nA) { bi = rowA; bj = rowA + g; }
    else        { bi = rowB; bj = rowB + (g - nA); }
    const int jbase = bj * 128;

    __syncthreads();                    // Bbuf[pb] = (g, half0) ready
    if (bi != cur_bi) {
      if (cur_bi >= 0) flush_rows();
      cur_bi = bi;
      stage_half(&Abuf[0][0], bi * 128, 0);
      stage_half(&Abuf[1][0], bi * 128, 1);
      stage_half(&Bbuf[pb ^ 1][0], jbase, 1);
      __syncthreads();                  // A staged (drains B-half1 early too)
      // A fragments -> registers (one-time ds_read pass per bi)
#pragma unroll
      for (int mi = 0; mi < 4; ++mi) {
        const int r = wr * 64 + mi * 16 + ln15;
#pragma unroll
        for (int kt = 0; kt < 8; ++kt) {
          const int c = ((kt & 3) * 4 + q) ^ (r & 7);
          af[mi][kt] = *(const bf16x8*)((const char*)&Abuf[kt >> 2][0] + r * 256 + c * 16);
        }
      }
#pragma unroll
      for (int mi = 0; mi < 4; ++mi)
#pragma unroll
        for (int rg = 0; rg < 4; ++rg)
          rowlab[mi * 4 + rg] = labels[bi * 128 + wr * 64 + mi * 16 + q * 4 + rg];
#pragma unroll
      for (int t = 0; t < 16; ++t) { rs[t] = 0.f; rp[t] = 0.f; }
    } else {
      stage_half(&Bbuf[pb ^ 1][0], jbase, 1);
    }

    int labJ[4];
#pragma unroll
    for (int ni = 0; ni < 4; ++ni)
      labJ[ni] = labels[jbase + wc * 64 + ni * 16 + ln15];

    f32x4 acc[4][4];
#pragma unroll
    for (int mi = 0; mi < 4; ++mi)
#pragma unroll
      for (int ni = 0; ni < 4; ++ni) acc[mi][ni] = (f32x4)0.0f;

    // compute one K-half (4 kt) from Bbuf[pbuf]
    auto compute_half = [&](int pbuf, int ks) {
#pragma unroll
      for (int kt2 = 0; kt2 < 4; ++kt2) {
        bf16x8 bfr[4];
#pragma unroll
        for (int ni = 0; ni < 4; ++ni) {
          const int n = wc * 64 + ni * 16 + ln15;
          const int c = (kt2 * 4 + q) ^ (n & 7);
          bfr[ni] = *(const bf16x8*)((const char*)&Bbuf[pbuf][0] + n * 256 + c * 16);
        }
#pragma unroll
        for (int mi = 0; mi < 4; ++mi)
#pragma unroll
          for (int ni = 0; ni < 4; ++ni)
            acc[mi][ni] = __builtin_amdgcn_mfma_f32_16x16x32_bf16(
                af[mi][ks + kt2], bfr[ni], acc[mi][ni], 0, 0, 0);
      }
    };

    compute_half(pb, 0);                // half 0: kt 0..3
    pb ^= 1;
    __syncthreads();                    // Bbuf[pb] = (g, half1) ready
    if (g + 1 < g1) {                   // prefetch next tile's half0
      int bin, bjn;
      const int gn = g + 1;
      if (gn < nA) { bin = rowA; bjn = rowA + gn; }
      else         { bin = rowB; bjn = rowB + (gn - nA); }
      (void)bin;
      stage_half(&Bbuf[pb ^ 1][0], bjn * 128, 0);
    }
    compute_half(pb, 4);                // half 1: kt 4..7
    pb ^= 1;

    // ---- epilogue: exp-sum + positive-sim (rows persist; cols via symmetry)
    float cs[4], cp[4];
#pragma unroll
    for (int t = 0; t < 4; ++t) { cs[t] = 0.f; cp[t] = 0.f; }
#pragma unroll
    for (int mi = 0; mi < 4; ++mi)
#pragma unroll
      for (int ni = 0; ni < 4; ++ni)
#pragma unroll
        for (int rg = 0; rg < 4; ++rg) {
          const float y = acc[mi][ni][rg];
          const float yc = fminf(CLAMP_Y, fmaxf(-CLAMP_Y, y));  // v_med3
          const float e = fast_exp2(yc - CLAMP_Y);
          const float pv = (labJ[ni] == rowlab[mi * 4 + rg]) ? yc : 0.0f;
          rs[mi * 4 + rg] += e;
          rp[mi * 4 + rg] += pv;
          cs[ni] += e;
          cp[ni] += pv;
        }

    if (bj != bi) {  // col sums -> rows of bj (both wr-waves atomic partials)
#pragma unroll
      for (int m = 16; m <= 32; m <<= 1)
#pragma unroll
        for (int t = 0; t < 4; ++t) {
          cs[t] += __shfl_xor(cs[t], m, 64);
          cp[t] += __shfl_xor(cp[t], m, 64);
        }
      if (q == 0) {
#pragma unroll
        for (int ni = 0; ni < 4; ++ni) {
          const int col = jbase + wc * 64 + ni * 16 + ln15;
          atomicAdd(&S[col], cs[ni]);
          atomicAdd(&P[col], cp[ni]);
        }
      }
    }
  }
  flush_rows();

  // ---- completion: last block performs the finalize ----
  __threadfence();
  __syncthreads();
  if (tid == 0) {
    const unsigned int old = __hip_atomic_fetch_add(done, 1u, __ATOMIC_ACQ_REL,
                                                    __HIP_MEMORY_SCOPE_AGENT);
    lastflag = (old == NBLK - 1) ? 1u : 0u;
  }
  __syncthreads();
  if (lastflag) {
    int* h = (int*)&Abuf[0][0];  // reuse LDS as label histogram
    if (tid < NCLS) h[tid] = 0;
    __syncthreads();
    for (int i = tid; i < N_ROWS; i += 256) atomicAdd(&h[labels[i]], 1);
    __syncthreads();
    float lsum = 0.f, vsum = 0.f;
    for (int i = tid; i < N_ROWS; i += 256) {
      const int cnt = h[labels[i]] - 1;  // positives excluding self
      if (cnt > 0) {
        const float s = __hip_atomic_load(&S[i], __ATOMIC_RELAXED,
                                          __HIP_MEMORY_SCOPE_AGENT);
        const float p = __hip_atomic_load(&P[i], __ATOMIC_RELAXED,
                                          __HIP_MEMORY_SCOPE_AGENT);
        const float lse = 10.0f + logf(s - 1.0f);   // remove diag e=1
        const float psum = p * LN2F - 10.0f;        // de-scale, remove diag
        lsum += lse - psum / (float)cnt;            // -mean_log_prob_pos
        vsum += 1.0f;
      }
    }
#pragma unroll
    for (int m = 32; m >= 1; m >>= 1) {
      lsum += __shfl_xor(lsum, m, 64);
      vsum += __shfl_xor(vsum, m, 64);
    }
    __shared__ float ls[4], vs[4];
    if (l == 0) { ls[w] = lsum; vs[w] = vsum; }
    __syncthreads();
    if (tid == 0) {
      float L = 0.f, V = 0.f;
      for (int k = 0; k < 4; ++k) { L += ls[k]; V += vs[k]; }
      out[0] = (V > 0.f) ? (L / fmaxf(V, 1.0f)) : 0.f;
    }
  }
}

extern "C" void kernel_launch(void* const* d_in, const int* in_sizes, int n_in,
                              void* d_out, int out_size, void* d_ws, size_t ws_size,
                              hipStream_t stream) {
  const float* feat = (const float*)d_in[0];
  const int* labels = (const int*)d_in[1];
  float* out = (float*)d_out;

  char* ws = (char*)d_ws;
  unsigned short* fnb = (unsigned short*)ws;            // bf16 [8192][256], 4 MB
  float* S = (float*)(ws + (size_t)N_ROWS * DIM * 2);   // [8192]
  float* P = S + N_ROWS;                                // [8192]
  unsigned int* done = (unsigned int*)(P + N_ROWS);     // [1]

  normalize_kernel<<<N_ROWS / 4, 256, 0, stream>>>(feat, fnb, S, P, done);
  simloss_tri<<<NBLK, 256, 0, stream>>>(fnb, labels, S, P, done, out);
}